// Round 7
// baseline (837.646 us; speedup 1.0000x reference)
//
#include <hip/hip_runtime.h>
#include <stdint.h>

// FFN: x[16384,1024] -> relu(x@W1^T+b1)[16384,4096] -> q_e4m3 -> @W2^T+b2 -> q_e5m10
// Round 9: GEMM1 single-buffered (64KB LDS) -> 2 blocks/CU. Rounds 3/4/6 showed
// the per-tile cost is the SERIAL sum of MFMA (2483cy/SIMD) and LDS traffic
// (~2300cy CU-shared): no within-block schedule overlapped them. The proven
// overlap mechanism is independent co-resident blocks (m114). 128KB dbuf locked
// us at 1 block/CU; dropping to a single 64KB buffer + __launch_bounds__(512,4)
// gives 2 blocks/CU (VGPR 104 <= 128). Per tile: {4 phases read+MFMA} -> bar ->
// stage t+1 -> vmcnt(0) -> bar; the exposed stage-wait is hidden by the other
// block's compute. GEMM1 grid=1024 guarantees 2/CU pairing.
// GEMM2 keeps the round-8 dbuf MX-fp8 form: its grid is exactly 256 (1/CU),
// so single-buffering it would expose the stage with no partner block.
// Numerics bit-identical (same MFMA sequence per acc element).

#define M_TOT 16384
#define D_DIM 1024
#define H_DIM 4096

typedef _Float16 f16x8 __attribute__((ext_vector_type(8)));
typedef _Float16 f16x4 __attribute__((ext_vector_type(4)));
typedef float f32x4 __attribute__((ext_vector_type(4)));
typedef int i32x4 __attribute__((ext_vector_type(4)));
typedef int i32x8 __attribute__((ext_vector_type(8)));

// global -> LDS direct copy, 16B per lane. LDS dest = wave-uniform base + lane*16.
__device__ __forceinline__ void gl16(const void* g, void* l) {
    __builtin_amdgcn_global_load_lds(
        (const __attribute__((address_space(1))) unsigned int*)(uintptr_t)g,
        (__attribute__((address_space(3))) unsigned int*)(unsigned int)(uintptr_t)l,
        16, 0, 0);
}

// positive-input e4m3 quantize (post-relu), division-free, RNE. Returns the
// quantized VALUE as f16 (exactly representable).
__device__ __forceinline__ _Float16 q_e4m3_pos(float v) {
    uint32_t t = __float_as_uint(v);
    uint32_t tn = (t + 0x7ffffu + ((t >> 20) & 1u)) & 0xfff00000u;
    float qn = __uint_as_float(tn);
    float qs = rintf(v * 512.0f) * 0.001953125f;
    return (_Float16)(v < 0.015625f ? qs : qn);
}

// ---- pre-pass: fp32 -> f16 (RNE), vectorized x4 ----
__global__ __launch_bounds__(256) void cvt_f16_kernel(
    const float* __restrict__ in, _Float16* __restrict__ out, int n4)
{
    int i = blockIdx.x * 256 + threadIdx.x;
    if (i >= n4) return;
    float4 v = reinterpret_cast<const float4*>(in)[i];
    f16x4 hv = {(_Float16)v.x, (_Float16)v.y, (_Float16)v.z, (_Float16)v.w};
    reinterpret_cast<f16x4*>(out)[i] = hv;
}

// ---- pre-pass: fp32 -> e4m3 BYTES via HW cvt (RNE, OCP grid == ref grid) ----
__global__ __launch_bounds__(256) void quant_e4m3_byte_kernel(
    const float* __restrict__ in, uint32_t* __restrict__ outq, int n4)
{
    int i = blockIdx.x * 256 + threadIdx.x;
    if (i >= n4) return;
    float4 v = reinterpret_cast<const float4*>(in)[i];
    uint32_t r = __builtin_amdgcn_cvt_pk_fp8_f32(v.x, v.y, 0, false);
    r = __builtin_amdgcn_cvt_pk_fp8_f32(v.z, v.w, r, true);
    outq[i] = r;
}

// ---- GEMM1: h=relu(xh@w1h^T+b1), q_e4m3, store BYTES. 256x256 BK=64 f16. ----
// Single-buffered 64KB LDS, 2 blocks/CU. Epilogue: q_e4m3 -> two 128-row
// half-tile f16 transposes through the 64KB buffer -> e4m3 bytes, coalesced.
__global__ __launch_bounds__(512, 4) void gemm1_f16(
    const _Float16* __restrict__ A, const _Float16* __restrict__ B,
    const float* __restrict__ bias, uint8_t* __restrict__ Cq)
{
    constexpr int K = D_DIM;   // 1024
    constexpr int N = H_DIM;   // 4096 (bytes per out row)
    __shared__ __align__(16) _Float16 smem[32768];   // 64 KiB
    _Float16* sA = smem;            // 16384 f16 = 32KB
    _Float16* sB = smem + 16384;    // 32KB

    const int tid  = threadIdx.x;
    const int lane = tid & 63;
    const int w    = tid >> 6;
    const int wr   = w >> 2, wc = w & 3;
    const int fr   = lane & 15, kq = lane >> 4;

    constexpr int NBX = N / 256;               // 16
    constexpr int NWG = (M_TOT / 256) * NBX;   // 1024
    constexpr int CPX = NWG / 8;
    int bid = blockIdx.y * NBX + blockIdx.x;
    bid = (bid & 7) * CPX + (bid >> 3);
    const int n0 = (bid % NBX) * 256;
    const int m0 = (bid / NBX) * 256;

    const int srow = tid >> 3;
    const int sseg = (tid & 7) ^ (srow & 7);
    const _Float16* gA = A + (size_t)(m0 + srow) * K + sseg * 8;
    const _Float16* gB = B + (size_t)(n0 + srow) * K + sseg * 8;
    const int ldsw = w * 512;
    const size_t R1 = (size_t)64 * K, R2 = (size_t)128 * K, R3 = (size_t)192 * K;

    const int xorv = fr & 7;
    const int cA0 = (kq ^ xorv) * 8;
    const int cA1 = ((kq + 4) ^ xorv) * 8;
    const int aRow = wr * 128 + fr;
    const int bRow = wc * 64 + fr;

    f32x4 acc[8][4];
#pragma unroll
    for (int i = 0; i < 8; i++)
#pragma unroll
        for (int j = 0; j < 4; j++) acc[i][j] = (f32x4){0.f, 0.f, 0.f, 0.f};

    f16x8 bfr[4][2];
    constexpr int NK = K / 64;   // 16

    // prologue: stage tile 0, drain, barrier.
    gl16(gB,      sB + ldsw);
    gl16(gB + R1, sB + 4096 + ldsw);
    gl16(gB + R2, sB + 8192 + ldsw);
    gl16(gB + R3, sB + 12288 + ldsw);
    gl16(gA,      sA + ldsw);
    gl16(gA + R1, sA + 4096 + ldsw);
    gl16(gA + R2, sA + 8192 + ldsw);
    gl16(gA + R3, sA + 12288 + ldsw);
    asm volatile("s_waitcnt vmcnt(0)" ::: "memory");
    __builtin_amdgcn_s_barrier();
    asm volatile("" ::: "memory");

    for (int t = 0; t < NK; ++t) {
        // compute tile t from the single buffer
#pragma unroll
        for (int p = 0; p < 4; ++p) {
            f16x8 afr[2][2];
#pragma unroll
            for (int ii = 0; ii < 2; ii++) {
                const _Float16* ra = sA + (aRow + (2 * p + ii) * 16) * 64;
                afr[ii][0] = *(const f16x8*)(ra + cA0);
                afr[ii][1] = *(const f16x8*)(ra + cA1);
            }
            if (p == 0) {
#pragma unroll
                for (int j = 0; j < 4; j++) {
                    const _Float16* rb = sB + (bRow + j * 16) * 64;
                    bfr[j][0] = *(const f16x8*)(rb + cA0);
                    bfr[j][1] = *(const f16x8*)(rb + cA1);
                }
            }
            __builtin_amdgcn_s_setprio(1);
#pragma unroll
            for (int ii = 0; ii < 2; ii++)
#pragma unroll
                for (int j = 0; j < 4; j++) {
                    acc[2*p+ii][j] = __builtin_amdgcn_mfma_f32_16x16x32_f16(
                        afr[ii][0], bfr[j][0], acc[2*p+ii][j], 0, 0, 0);
                    acc[2*p+ii][j] = __builtin_amdgcn_mfma_f32_16x16x32_f16(
                        afr[ii][1], bfr[j][1], acc[2*p+ii][j], 0, 0, 0);
                }
            __builtin_amdgcn_s_setprio(0);
        }

        // all waves done reading tile t
        asm volatile("" ::: "memory");
        __builtin_amdgcn_s_barrier();
        asm volatile("" ::: "memory");

        if (t + 1 < NK) {
            // stage tile t+1 into the same buffer; the vmcnt(0) wait is dead
            // time for THIS block, covered by the co-resident block's compute.
            const _Float16* gAn = gA + (size_t)(t + 1) * 64;
            const _Float16* gBn = gB + (size_t)(t + 1) * 64;
            gl16(gBn,      sB + ldsw);
            gl16(gBn + R1, sB + 4096 + ldsw);
            gl16(gBn + R2, sB + 8192 + ldsw);
            gl16(gBn + R3, sB + 12288 + ldsw);
            gl16(gAn,      sA + ldsw);
            gl16(gAn + R1, sA + 4096 + ldsw);
            gl16(gAn + R2, sA + 8192 + ldsw);
            gl16(gAn + R3, sA + 12288 + ldsw);
            asm volatile("s_waitcnt vmcnt(0)" ::: "memory");
            __builtin_amdgcn_s_barrier();
            asm volatile("" ::: "memory");
        }
    }

    // epilogue: +bias, relu, q_e4m3 (f16 value) -> swizzled 64KB LDS half-tile
    // [128][256] f16 -> read f16x8, cvt to e4m3 bytes, coalesced 8B stores.
    const int col0 = n0 + wc * 64 + fr;
    float bv[4];
#pragma unroll
    for (int j = 0; j < 4; j++) bv[j] = bias[col0 + j * 16];
    const int sub = (fr & 7) * 2;
    const int slotbase = wc * 8 + (fr >> 3);
    const int rowrel0 = kq * 4;               // + i*16 + r (0..127 within half)
#pragma unroll
    for (int half = 0; half < 2; ++half) {
        if (wr == half) {
#pragma unroll
            for (int i = 0; i < 8; i++) {
                const int trow0 = rowrel0 + i * 16;
#pragma unroll
                for (int r = 0; r < 4; r++) {
                    const int trow = trow0 + r;
                    const int swz = ((kq & 1) * 4 + r) ^ (kq >> 1);  // (trow&7)^((trow>>3)&1)
#pragma unroll
                    for (int j = 0; j < 4; j++) {
                        float v = fmaxf(acc[i][j][r] + bv[j], 0.0f);
                        _Float16 q = q_e4m3_pos(v);
                        int byte = trow * 512 + (((slotbase + j * 2) ^ swz) << 4) + sub;
                        *(_Float16*)((char*)smem + byte) = q;
                    }
                }
            }
        }
        __syncthreads();
#pragma unroll
        for (int cch = 0; cch < 8; cch++) {
            int flat = cch * 512 + tid;          // 16B-chunk index, 4096 per half
            int row  = flat >> 5;                // 0..127
            int slot = flat & 31;
            int swz  = (row & 7) ^ ((row >> 3) & 1);
            f16x8 v8 = *(const f16x8*)((char*)smem + row * 512 + ((slot ^ swz) << 4));
            uint32_t u0 = __builtin_amdgcn_cvt_pk_fp8_f32((float)v8[0], (float)v8[1], 0, false);
            u0 = __builtin_amdgcn_cvt_pk_fp8_f32((float)v8[2], (float)v8[3], u0, true);
            uint32_t u1 = __builtin_amdgcn_cvt_pk_fp8_f32((float)v8[4], (float)v8[5], 0, false);
            u1 = __builtin_amdgcn_cvt_pk_fp8_f32((float)v8[6], (float)v8[7], u1, true);
            uint2 u = {u0, u1};
            *(uint2*)(Cq + (size_t)(m0 + half * 128 + row) * N + n0 + slot * 8) = u;
        }
        if (half == 0) __syncthreads();
    }
}

// ---- GEMM2: out = hq @ wq^T + b2q (MX-fp8, unit scales), q_e5m10, fp32 out ----
// A[16384,4096] bytes, B[1024,4096] bytes, NT. 256x256 tile, BK=128 bytes.
// Round-8 form (double-buffered 128KB): grid is exactly 256 (1 block/CU), so
// there is no partner block to hide a single-buffer stage-wait behind.
__global__ __launch_bounds__(512) void gemm2_fp8(
    const uint8_t* __restrict__ A, const uint8_t* __restrict__ B,
    const float* __restrict__ b2, float* __restrict__ C)
{
    constexpr int Kb = H_DIM;  // 4096 bytes per row
    constexpr int N  = D_DIM;  // 1024
    __shared__ __align__(16) uint8_t smem[131072];
    uint8_t* sA = smem;            // 2 x 32768
    uint8_t* sB = smem + 65536;    // 2 x 32768

    const int tid  = threadIdx.x;
    const int lane = tid & 63;
    const int w    = tid >> 6;
    const int wr   = w >> 2, wc = w & 3;
    const int fr   = lane & 15, kq = lane >> 4;

    constexpr int NBX = N / 256;               // 4
    constexpr int NWG = (M_TOT / 256) * NBX;   // 256
    constexpr int CPX = NWG / 8;
    int bid = blockIdx.y * NBX + blockIdx.x;
    bid = (bid & 7) * CPX + (bid >> 3);
    const int n0 = (bid % NBX) * 256;
    const int m0 = (bid / NBX) * 256;

    const int srow = tid >> 3;
    const int sseg = (tid & 7) ^ (srow & 7);     // 16B-slot pre-swizzle
    const uint8_t* gA = A + (size_t)(m0 + srow) * Kb + sseg * 16;
    const uint8_t* gB = B + (size_t)(n0 + srow) * Kb + sseg * 16;
    const int ldsw = w * 1024;                   // bytes per wave per round
    const size_t R1 = (size_t)64 * Kb, R2 = (size_t)128 * Kb, R3 = (size_t)192 * Kb;

    const int xorv = fr & 7;
    const int sO0 = ((2 * kq) ^ xorv) * 16;
    const int sO1 = ((2 * kq + 1) ^ xorv) * 16;
    const int aRowB = (wr * 128 + fr) * 128;
    const int bRowB = (wc * 64 + fr) * 128;

    f32x4 acc[8][4];
#pragma unroll
    for (int i = 0; i < 8; i++)
#pragma unroll
        for (int j = 0; j < 4; j++) acc[i][j] = (f32x4){0.f, 0.f, 0.f, 0.f};

    i32x8 bfr[4];
    constexpr int NK = Kb / 128;   // 32
    constexpr uint32_t SC1 = 0x7f7f7f7fu;   // e8m0 unit scale in every byte

    gl16(gB,      sB + ldsw);
    gl16(gB + R1, sB + 8192 + ldsw);
    gl16(gB + R2, sB + 16384 + ldsw);
    gl16(gB + R3, sB + 24576 + ldsw);
    gl16(gA,      sA + ldsw);
    gl16(gA + R1, sA + 8192 + ldsw);
    gl16(gA + R2, sA + 16384 + ldsw);
    gl16(gA + R3, sA + 24576 + ldsw);
    asm volatile("s_waitcnt vmcnt(0)" ::: "memory");
    __builtin_amdgcn_s_barrier();
    asm volatile("" ::: "memory");

    for (int t = 0; t < NK; ++t) {
        const int c = t & 1;
        const uint8_t* sAc = sA + c * 32768;
        const uint8_t* sBc = sB + c * 32768;
        uint8_t* sAn = sA + (c ^ 1) * 32768;
        uint8_t* sBn = sB + (c ^ 1) * 32768;
        const bool pref = (t + 1 < NK);

        if (pref) {
            const uint8_t* gAn = gA + (size_t)(t + 1) * 128;
            const uint8_t* gBn = gB + (size_t)(t + 1) * 128;
            gl16(gBn,      sBn + ldsw);
            gl16(gBn + R1, sBn + 8192 + ldsw);
            gl16(gBn + R2, sBn + 16384 + ldsw);
            gl16(gBn + R3, sBn + 24576 + ldsw);
            gl16(gAn,      sAn + ldsw);
            gl16(gAn + R1, sAn + 8192 + ldsw);
            gl16(gAn + R2, sAn + 16384 + ldsw);
            gl16(gAn + R3, sAn + 24576 + ldsw);
        }

#pragma unroll
        for (int p = 0; p < 4; ++p) {
            i32x8 af[2];
#pragma unroll
            for (int ii = 0; ii < 2; ii++) {
                const uint8_t* ra = sAc + aRowB + (2 * p + ii) * 2048;
                i32x4 lo = *(const i32x4*)(ra + sO0);
                i32x4 hi = *(const i32x4*)(ra + sO1);
                af[ii] = (i32x8){lo.x, lo.y, lo.z, lo.w, hi.x, hi.y, hi.z, hi.w};
            }
            if (p == 0) {
#pragma unroll
                for (int j = 0; j < 4; j++) {
                    const uint8_t* rb = sBc + bRowB + j * 2048;
                    i32x4 lo = *(const i32x4*)(rb + sO0);
                    i32x4 hi = *(const i32x4*)(rb + sO1);
                    bfr[j] = (i32x8){lo.x, lo.y, lo.z, lo.w, hi.x, hi.y, hi.z, hi.w};
                }
            }
            __builtin_amdgcn_s_setprio(1);
#pragma unroll
            for (int ii = 0; ii < 2; ii++)
#pragma unroll
                for (int j = 0; j < 4; j++) {
                    acc[2*p+ii][j] = __builtin_amdgcn_mfma_scale_f32_16x16x128_f8f6f4(
                        af[ii], bfr[j], acc[2*p+ii][j],
                        0, 0,            // cbsz=FP8, blgp=FP8
                        0, SC1,          // opsel_a, scale_a (1.0)
                        0, SC1);         // opsel_b, scale_b (1.0)
                }
            __builtin_amdgcn_s_setprio(0);
        }

        asm volatile("s_waitcnt vmcnt(0)" ::: "memory");
        __builtin_amdgcn_s_barrier();
        asm volatile("" ::: "memory");
    }

    // epilogue: + q_e5m10(b2), quantize e5m10 (f16 RNE roundtrip), store fp32
    const int col0 = n0 + wc * 64 + fr;
    const int row0 = m0 + wr * 128 + kq * 4;
#pragma unroll
    for (int j = 0; j < 4; j++) {
        const float bq = (float)(_Float16)b2[col0 + j * 16];
#pragma unroll
        for (int i = 0; i < 8; i++) {
            size_t base = (size_t)(row0 + i * 16) * N + (col0 + j * 16);
#pragma unroll
            for (int r = 0; r < 4; r++) {
                float v = acc[i][j][r] + bq;
                C[base + (size_t)r * N] = (float)(_Float16)v;
            }
        }
    }
}

extern "C" void kernel_launch(void* const* d_in, const int* in_sizes, int n_in,
                              void* d_out, int out_size, void* d_ws, size_t ws_size,
                              hipStream_t stream) {
    const float* x  = (const float*)d_in[0];   // [16384,1024]
    const float* w1 = (const float*)d_in[1];   // [4096,1024]
    const float* b1 = (const float*)d_in[2];   // [4096]
    const float* w2 = (const float*)d_in[3];   // [1024,4096]
    const float* b2 = (const float*)d_in[4];   // [1024]
    float* out = (float*)d_out;

    // workspace layout (bytes):
    // hq  e4m3 bytes [16384,4096] :  67,108,864
    // xh  f16 [16384,1024]        :  33,554,432
    // w1h f16 [4096,1024]         :   8,388,608
    // wq  e4m3 bytes [1024,4096]  :   4,194,304
    const size_t need = 67108864ull + 33554432ull + 8388608ull + 4194304ull;
    if (ws_size < need) return;  // fail visibly (output stays zero)

    char* ws = (char*)d_ws;
    uint8_t*  hq  = (uint8_t*)ws;
    _Float16* xh  = (_Float16*)(ws + 67108864ull);
    _Float16* w1h = xh + 16777216;
    uint8_t*  wq  = (uint8_t*)(w1h + 4194304);

    cvt_f16_kernel<<<16384, 256, 0, stream>>>(x, xh, 4194304);
    cvt_f16_kernel<<<4096, 256, 0, stream>>>(w1, w1h, 1048576);
    quant_e4m3_byte_kernel<<<4096, 256, 0, stream>>>(w2, (uint32_t*)wq, 1048576);

    // GEMM1: M=16384, N=4096, K=1024 -> grid (16,64) = 1024 wg, 2 blocks/CU
    gemm1_f16<<<dim3(H_DIM / 256, M_TOT / 256), 512, 0, stream>>>(xh, w1h, b1, hq);
    // GEMM2: M=16384, N=1024, K=4096 bytes -> grid (4,64) = 256 wg
    gemm2_fp8<<<dim3(D_DIM / 256, M_TOT / 256), 512, 0, stream>>>(hq, wq, b2, out);
}

// Round 8
// 247.332 us; speedup vs baseline: 3.3867x; 3.3867x over previous
//
#include <hip/hip_runtime.h>
#include <stdint.h>

// FFN: x[16384,1024] -> relu(x@W1^T+b1)[16384,4096] -> q_e4m3 -> @W2^T+b2 -> q_e5m10
// Round 10: register read-ahead pipelining. Base = round-8 (246us best: f16
// GEMM1 dbuf barrier-light + MX-fp8 GEMM2). Both GEMMs showed serial
// per-phase {ds_read -> lgkmcnt -> MFMA}: LDS unit bursts while matrix pipes
// idle, then vice versa (MfmaUtil ~40% = MFMA/(MFMA+LDS) exactly). Fix: A-frag
// register ping-pong (afr[2]/af[2] indexed p&1, fully unrolled -> static):
// phase p issues p+1's reads BEFORE p's MFMAs, so the compiler's counted
// lgkmcnt waits only on phase-old reads and the LDS unit works under the MFMA
// window. Accumulation order unchanged -> bit-identical output.
// Round-9's __launch_bounds__(512,4) REVERTED (capped VGPR at 128 < acc's 128
// + operands -> scratch spill, 2GB writes, 5x regression).

#define M_TOT 16384
#define D_DIM 1024
#define H_DIM 4096

typedef _Float16 f16x8 __attribute__((ext_vector_type(8)));
typedef _Float16 f16x4 __attribute__((ext_vector_type(4)));
typedef float f32x4 __attribute__((ext_vector_type(4)));
typedef int i32x4 __attribute__((ext_vector_type(4)));
typedef int i32x8 __attribute__((ext_vector_type(8)));

// global -> LDS direct copy, 16B per lane. LDS dest = wave-uniform base + lane*16.
__device__ __forceinline__ void gl16(const void* g, void* l) {
    __builtin_amdgcn_global_load_lds(
        (const __attribute__((address_space(1))) unsigned int*)(uintptr_t)g,
        (__attribute__((address_space(3))) unsigned int*)(unsigned int)(uintptr_t)l,
        16, 0, 0);
}

// positive-input e4m3 quantize (post-relu), division-free, RNE. Returns the
// quantized VALUE as f16 (exactly representable).
__device__ __forceinline__ _Float16 q_e4m3_pos(float v) {
    uint32_t t = __float_as_uint(v);
    uint32_t tn = (t + 0x7ffffu + ((t >> 20) & 1u)) & 0xfff00000u;
    float qn = __uint_as_float(tn);
    float qs = rintf(v * 512.0f) * 0.001953125f;
    return (_Float16)(v < 0.015625f ? qs : qn);
}

// ---- pre-pass: fp32 -> f16 (RNE), vectorized x4 ----
__global__ __launch_bounds__(256) void cvt_f16_kernel(
    const float* __restrict__ in, _Float16* __restrict__ out, int n4)
{
    int i = blockIdx.x * 256 + threadIdx.x;
    if (i >= n4) return;
    float4 v = reinterpret_cast<const float4*>(in)[i];
    f16x4 hv = {(_Float16)v.x, (_Float16)v.y, (_Float16)v.z, (_Float16)v.w};
    reinterpret_cast<f16x4*>(out)[i] = hv;
}

// ---- pre-pass: fp32 -> e4m3 BYTES via HW cvt (RNE, OCP grid == ref grid) ----
__global__ __launch_bounds__(256) void quant_e4m3_byte_kernel(
    const float* __restrict__ in, uint32_t* __restrict__ outq, int n4)
{
    int i = blockIdx.x * 256 + threadIdx.x;
    if (i >= n4) return;
    float4 v = reinterpret_cast<const float4*>(in)[i];
    uint32_t r = __builtin_amdgcn_cvt_pk_fp8_f32(v.x, v.y, 0, false);
    r = __builtin_amdgcn_cvt_pk_fp8_f32(v.z, v.w, r, true);
    outq[i] = r;
}

// ---- GEMM1: h=relu(xh@w1h^T+b1), q_e4m3, store BYTES. 256x256 BK=64 f16. ----
// Double-buffered 128KB, barrier-light K-loop + A-frag read-ahead ping-pong.
__global__ __launch_bounds__(512) void gemm1_f16(
    const _Float16* __restrict__ A, const _Float16* __restrict__ B,
    const float* __restrict__ bias, uint8_t* __restrict__ Cq)
{
    constexpr int K = D_DIM;   // 1024
    constexpr int N = H_DIM;   // 4096 (bytes per out row)
    __shared__ __align__(16) _Float16 smem[65536];   // 128 KiB
    _Float16* sA = smem;            // 2 x 16384
    _Float16* sB = smem + 32768;    // 2 x 16384

    const int tid  = threadIdx.x;
    const int lane = tid & 63;
    const int w    = tid >> 6;
    const int wr   = w >> 2, wc = w & 3;
    const int fr   = lane & 15, kq = lane >> 4;

    constexpr int NBX = N / 256;               // 16
    constexpr int NWG = (M_TOT / 256) * NBX;   // 1024
    constexpr int CPX = NWG / 8;
    int bid = blockIdx.y * NBX + blockIdx.x;
    bid = (bid & 7) * CPX + (bid >> 3);
    const int n0 = (bid % NBX) * 256;
    const int m0 = (bid / NBX) * 256;

    const int srow = tid >> 3;
    const int sseg = (tid & 7) ^ (srow & 7);
    const _Float16* gA = A + (size_t)(m0 + srow) * K + sseg * 8;
    const _Float16* gB = B + (size_t)(n0 + srow) * K + sseg * 8;
    const int ldsw = w * 512;
    const size_t R1 = (size_t)64 * K, R2 = (size_t)128 * K, R3 = (size_t)192 * K;

    const int xorv = fr & 7;
    const int cA0 = (kq ^ xorv) * 8;
    const int cA1 = ((kq + 4) ^ xorv) * 8;
    const int aRow = wr * 128 + fr;
    const int bRow = wc * 64 + fr;

    f32x4 acc[8][4];
#pragma unroll
    for (int i = 0; i < 8; i++)
#pragma unroll
        for (int j = 0; j < 4; j++) acc[i][j] = (f32x4){0.f, 0.f, 0.f, 0.f};

    f16x8 bfr[4][2];
    constexpr int NK = K / 64;   // 16

    gl16(gB,      sB + ldsw);
    gl16(gB + R1, sB + 4096 + ldsw);
    gl16(gB + R2, sB + 8192 + ldsw);
    gl16(gB + R3, sB + 12288 + ldsw);
    gl16(gA,      sA + ldsw);
    gl16(gA + R1, sA + 4096 + ldsw);
    gl16(gA + R2, sA + 8192 + ldsw);
    gl16(gA + R3, sA + 12288 + ldsw);
    asm volatile("s_waitcnt vmcnt(0)" ::: "memory");
    __builtin_amdgcn_s_barrier();
    asm volatile("" ::: "memory");

    for (int t = 0; t < NK; ++t) {
        const int c = t & 1;
        const _Float16* sAc = sA + c * 16384;
        const _Float16* sBc = sB + c * 16384;
        _Float16* sAn = sA + (c ^ 1) * 16384;
        _Float16* sBn = sB + (c ^ 1) * 16384;
        const bool pref = (t + 1 < NK);

        if (pref) {
            const _Float16* gAn = gA + (size_t)(t + 1) * 64;
            const _Float16* gBn = gB + (size_t)(t + 1) * 64;
            gl16(gBn,      sBn + ldsw);
            gl16(gBn + R1, sBn + 4096 + ldsw);
            gl16(gBn + R2, sBn + 8192 + ldsw);
            gl16(gBn + R3, sBn + 12288 + ldsw);
            gl16(gAn,      sAn + ldsw);
            gl16(gAn + R1, sAn + 4096 + ldsw);
            gl16(gAn + R2, sAn + 8192 + ldsw);
            gl16(gAn + R3, sAn + 12288 + ldsw);
        }

        // A-frag ping-pong: afr[p&1] consumed, afr[(p+1)&1] prefetched.
        f16x8 afr[2][2][2];
        // tile prologue: B (8 reads) + A phase-0 (4 reads)
#pragma unroll
        for (int ii = 0; ii < 2; ii++) {
            const _Float16* ra = sAc + (aRow + ii * 16) * 64;
            afr[0][ii][0] = *(const f16x8*)(ra + cA0);
            afr[0][ii][1] = *(const f16x8*)(ra + cA1);
        }
#pragma unroll
        for (int j = 0; j < 4; j++) {
            const _Float16* rb = sBc + (bRow + j * 16) * 64;
            bfr[j][0] = *(const f16x8*)(rb + cA0);
            bfr[j][1] = *(const f16x8*)(rb + cA1);
        }
#pragma unroll
        for (int p = 0; p < 4; ++p) {
            const int cur = p & 1, nxt = cur ^ 1;
            if (p < 3) {
                // issue phase p+1's reads BEFORE phase p's MFMAs
#pragma unroll
                for (int ii = 0; ii < 2; ii++) {
                    const _Float16* ra = sAc + (aRow + (2 * (p + 1) + ii) * 16) * 64;
                    afr[nxt][ii][0] = *(const f16x8*)(ra + cA0);
                    afr[nxt][ii][1] = *(const f16x8*)(ra + cA1);
                }
            }
            __builtin_amdgcn_s_setprio(1);
#pragma unroll
            for (int ii = 0; ii < 2; ii++)
#pragma unroll
                for (int j = 0; j < 4; j++) {
                    acc[2*p+ii][j] = __builtin_amdgcn_mfma_f32_16x16x32_f16(
                        afr[cur][ii][0], bfr[j][0], acc[2*p+ii][j], 0, 0, 0);
                    acc[2*p+ii][j] = __builtin_amdgcn_mfma_f32_16x16x32_f16(
                        afr[cur][ii][1], bfr[j][1], acc[2*p+ii][j], 0, 0, 0);
                }
            __builtin_amdgcn_s_setprio(0);
        }

        asm volatile("s_waitcnt vmcnt(0)" ::: "memory");
        __builtin_amdgcn_s_barrier();
        asm volatile("" ::: "memory");
    }

    // epilogue: +bias, relu, q_e4m3 (f16 value) -> swizzled LDS [256][256] f16
    // tile -> read f16x8, convert to 8 e4m3 bytes (exact), coalesced 8B stores.
    const int col0 = n0 + wc * 64 + fr;
    float bv[4];
#pragma unroll
    for (int j = 0; j < 4; j++) bv[j] = bias[col0 + j * 16];
    const int sub = (fr & 7) * 2;
    const int slotbase = wc * 8 + (fr >> 3);
    const int rowbase = wr * 128 + kq * 4;
#pragma unroll
    for (int i = 0; i < 8; i++) {
        const int trow0 = rowbase + i * 16;
#pragma unroll
        for (int r = 0; r < 4; r++) {
            const int trow = trow0 + r;
            const int swz = (((kq & 1) * 4 + r)) ^ (kq >> 1);  // == (trow&7)^((trow>>3)&1)
#pragma unroll
            for (int j = 0; j < 4; j++) {
                float v = fmaxf(acc[i][j][r] + bv[j], 0.0f);
                _Float16 q = q_e4m3_pos(v);
                int byte = trow * 512 + (((slotbase + j * 2) ^ swz) << 4) + sub;
                *(_Float16*)((char*)smem + byte) = q;
            }
        }
    }
    __syncthreads();
#pragma unroll
    for (int cch = 0; cch < 16; cch++) {
        int flat = cch * 512 + tid;
        int row  = flat >> 5;
        int slot = flat & 31;
        int swz  = (row & 7) ^ ((row >> 3) & 1);
        f16x8 v8 = *(const f16x8*)((char*)smem + row * 512 + ((slot ^ swz) << 4));
        uint32_t u0 = __builtin_amdgcn_cvt_pk_fp8_f32((float)v8[0], (float)v8[1], 0, false);
        u0 = __builtin_amdgcn_cvt_pk_fp8_f32((float)v8[2], (float)v8[3], u0, true);
        uint32_t u1 = __builtin_amdgcn_cvt_pk_fp8_f32((float)v8[4], (float)v8[5], 0, false);
        u1 = __builtin_amdgcn_cvt_pk_fp8_f32((float)v8[6], (float)v8[7], u1, true);
        uint2 u = {u0, u1};
        *(uint2*)(Cq + (size_t)(m0 + row) * N + n0 + slot * 8) = u;
    }
}

// ---- GEMM2: out = hq @ wq^T + b2q (MX-fp8, unit scales), q_e5m10, fp32 out ----
// A[16384,4096] bytes, B[1024,4096] bytes, NT. 256x256 tile, BK=128 bytes.
// Round-8 dbuf form + A-frag read-ahead ping-pong.
__global__ __launch_bounds__(512) void gemm2_fp8(
    const uint8_t* __restrict__ A, const uint8_t* __restrict__ B,
    const float* __restrict__ b2, float* __restrict__ C)
{
    constexpr int Kb = H_DIM;  // 4096 bytes per row
    constexpr int N  = D_DIM;  // 1024
    __shared__ __align__(16) uint8_t smem[131072];
    uint8_t* sA = smem;            // 2 x 32768
    uint8_t* sB = smem + 65536;    // 2 x 32768

    const int tid  = threadIdx.x;
    const int lane = tid & 63;
    const int w    = tid >> 6;
    const int wr   = w >> 2, wc = w & 3;
    const int fr   = lane & 15, kq = lane >> 4;

    constexpr int NBX = N / 256;               // 4
    constexpr int NWG = (M_TOT / 256) * NBX;   // 256
    constexpr int CPX = NWG / 8;
    int bid = blockIdx.y * NBX + blockIdx.x;
    bid = (bid & 7) * CPX + (bid >> 3);
    const int n0 = (bid % NBX) * 256;
    const int m0 = (bid / NBX) * 256;

    const int srow = tid >> 3;
    const int sseg = (tid & 7) ^ (srow & 7);     // 16B-slot pre-swizzle
    const uint8_t* gA = A + (size_t)(m0 + srow) * Kb + sseg * 16;
    const uint8_t* gB = B + (size_t)(n0 + srow) * Kb + sseg * 16;
    const int ldsw = w * 1024;                   // bytes per wave per round
    const size_t R1 = (size_t)64 * Kb, R2 = (size_t)128 * Kb, R3 = (size_t)192 * Kb;

    const int xorv = fr & 7;
    const int sO0 = ((2 * kq) ^ xorv) * 16;
    const int sO1 = ((2 * kq + 1) ^ xorv) * 16;
    const int aRowB = (wr * 128 + fr) * 128;
    const int bRowB = (wc * 64 + fr) * 128;

    f32x4 acc[8][4];
#pragma unroll
    for (int i = 0; i < 8; i++)
#pragma unroll
        for (int j = 0; j < 4; j++) acc[i][j] = (f32x4){0.f, 0.f, 0.f, 0.f};

    i32x8 bfr[4];
    constexpr int NK = Kb / 128;   // 32
    constexpr uint32_t SC1 = 0x7f7f7f7fu;   // e8m0 unit scale in every byte

    gl16(gB,      sB + ldsw);
    gl16(gB + R1, sB + 8192 + ldsw);
    gl16(gB + R2, sB + 16384 + ldsw);
    gl16(gB + R3, sB + 24576 + ldsw);
    gl16(gA,      sA + ldsw);
    gl16(gA + R1, sA + 8192 + ldsw);
    gl16(gA + R2, sA + 16384 + ldsw);
    gl16(gA + R3, sA + 24576 + ldsw);
    asm volatile("s_waitcnt vmcnt(0)" ::: "memory");
    __builtin_amdgcn_s_barrier();
    asm volatile("" ::: "memory");

    for (int t = 0; t < NK; ++t) {
        const int c = t & 1;
        const uint8_t* sAc = sA + c * 32768;
        const uint8_t* sBc = sB + c * 32768;
        uint8_t* sAn = sA + (c ^ 1) * 32768;
        uint8_t* sBn = sB + (c ^ 1) * 32768;
        const bool pref = (t + 1 < NK);

        if (pref) {
            const uint8_t* gAn = gA + (size_t)(t + 1) * 128;
            const uint8_t* gBn = gB + (size_t)(t + 1) * 128;
            gl16(gBn,      sBn + ldsw);
            gl16(gBn + R1, sBn + 8192 + ldsw);
            gl16(gBn + R2, sBn + 16384 + ldsw);
            gl16(gBn + R3, sBn + 24576 + ldsw);
            gl16(gAn,      sAn + ldsw);
            gl16(gAn + R1, sAn + 8192 + ldsw);
            gl16(gAn + R2, sAn + 16384 + ldsw);
            gl16(gAn + R3, sAn + 24576 + ldsw);
        }

        // A-frag ping-pong: af[p&1] consumed, af[(p+1)&1] prefetched.
        i32x8 af[2][2];
#pragma unroll
        for (int ii = 0; ii < 2; ii++) {
            const uint8_t* ra = sAc + aRowB + ii * 2048;
            i32x4 lo = *(const i32x4*)(ra + sO0);
            i32x4 hi = *(const i32x4*)(ra + sO1);
            af[0][ii] = (i32x8){lo.x, lo.y, lo.z, lo.w, hi.x, hi.y, hi.z, hi.w};
        }
#pragma unroll
        for (int j = 0; j < 4; j++) {
            const uint8_t* rb = sBc + bRowB + j * 2048;
            i32x4 lo = *(const i32x4*)(rb + sO0);
            i32x4 hi = *(const i32x4*)(rb + sO1);
            bfr[j] = (i32x8){lo.x, lo.y, lo.z, lo.w, hi.x, hi.y, hi.z, hi.w};
        }
#pragma unroll
        for (int p = 0; p < 4; ++p) {
            const int cur = p & 1, nxt = cur ^ 1;
            if (p < 3) {
#pragma unroll
                for (int ii = 0; ii < 2; ii++) {
                    const uint8_t* ra = sAc + aRowB + (2 * (p + 1) + ii) * 2048;
                    i32x4 lo = *(const i32x4*)(ra + sO0);
                    i32x4 hi = *(const i32x4*)(ra + sO1);
                    af[nxt][ii] = (i32x8){lo.x, lo.y, lo.z, lo.w, hi.x, hi.y, hi.z, hi.w};
                }
            }
            __builtin_amdgcn_s_setprio(1);
#pragma unroll
            for (int ii = 0; ii < 2; ii++)
#pragma unroll
                for (int j = 0; j < 4; j++) {
                    acc[2*p+ii][j] = __builtin_amdgcn_mfma_scale_f32_16x16x128_f8f6f4(
                        af[cur][ii], bfr[j], acc[2*p+ii][j],
                        0, 0,            // cbsz=FP8, blgp=FP8
                        0, SC1,          // opsel_a, scale_a (1.0)
                        0, SC1);         // opsel_b, scale_b (1.0)
                }
            __builtin_amdgcn_s_setprio(0);
        }

        asm volatile("s_waitcnt vmcnt(0)" ::: "memory");
        __builtin_amdgcn_s_barrier();
        asm volatile("" ::: "memory");
    }

    // epilogue: + q_e5m10(b2), quantize e5m10 (f16 RNE roundtrip), store fp32
    const int col0 = n0 + wc * 64 + fr;
    const int row0 = m0 + wr * 128 + kq * 4;
#pragma unroll
    for (int j = 0; j < 4; j++) {
        const float bq = (float)(_Float16)b2[col0 + j * 16];
#pragma unroll
        for (int i = 0; i < 8; i++) {
            size_t base = (size_t)(row0 + i * 16) * N + (col0 + j * 16);
#pragma unroll
            for (int r = 0; r < 4; r++) {
                float v = acc[i][j][r] + bq;
                C[base + (size_t)r * N] = (float)(_Float16)v;
            }
        }
    }
}

extern "C" void kernel_launch(void* const* d_in, const int* in_sizes, int n_in,
                              void* d_out, int out_size, void* d_ws, size_t ws_size,
                              hipStream_t stream) {
    const float* x  = (const float*)d_in[0];   // [16384,1024]
    const float* w1 = (const float*)d_in[1];   // [4096,1024]
    const float* b1 = (const float*)d_in[2];   // [4096]
    const float* w2 = (const float*)d_in[3];   // [1024,4096]
    const float* b2 = (const float*)d_in[4];   // [1024]
    float* out = (float*)d_out;

    // workspace layout (bytes):
    // hq  e4m3 bytes [16384,4096] :  67,108,864
    // xh  f16 [16384,1024]        :  33,554,432
    // w1h f16 [4096,1024]         :   8,388,608
    // wq  e4m3 bytes [1024,4096]  :   4,194,304
    const size_t need = 67108864ull + 33554432ull + 8388608ull + 4194304ull;
    if (ws_size < need) return;  // fail visibly (output stays zero)

    char* ws = (char*)d_ws;
    uint8_t*  hq  = (uint8_t*)ws;
    _Float16* xh  = (_Float16*)(ws + 67108864ull);
    _Float16* w1h = xh + 16777216;
    uint8_t*  wq  = (uint8_t*)(w1h + 4194304);

    cvt_f16_kernel<<<16384, 256, 0, stream>>>(x, xh, 4194304);
    cvt_f16_kernel<<<4096, 256, 0, stream>>>(w1, w1h, 1048576);
    quant_e4m3_byte_kernel<<<4096, 256, 0, stream>>>(w2, (uint32_t*)wq, 1048576);

    // GEMM1: M=16384, N=4096, K=1024 -> grid (16,64) = 1024 wg
    gemm1_f16<<<dim3(H_DIM / 256, M_TOT / 256), 512, 0, stream>>>(xh, w1h, b1, hq);
    // GEMM2: M=16384, N=1024, K=4096 bytes -> grid (4,64) = 256 wg
    gemm2_fp8<<<dim3(D_DIM / 256, M_TOT / 256), 512, 0, stream>>>(hq, wq, b2, out);
}

// Round 9
// 233.812 us; speedup vs baseline: 3.5826x; 1.0578x over previous
//
#include <hip/hip_runtime.h>
#include <stdint.h>

// FFN: x[16384,1024] -> relu(x@W1^T+b1)[16384,4096] -> q_e4m3 -> @W2^T+b2 -> q_e5m10
// Round 11: remove setprio from the K-loops + pin read-ahead with
// sched_barrier(0). Analysis: m201's 62% MfmaUtil is itself a SERIAL sum
// (2483 MFMA + ~1536 LDS@128B/cyc); our 41% = same MFMA + LDS at ~85-100B/cyc.
// Suspected LDS-rate killers: (1) s_setprio(1) around MFMA starves the OTHER
// waves' ds_read issue in our drifted (barrier-light) schedule — T5 is known
// ~0/negative on non-phase-locked GEMM (m190); (2) hipcc sinks the read-ahead
// back to its consumers — sched_barrier(0) pins reads above the MFMA cluster.
// Both changes numerics-free: accumulation order untouched -> bit-identical.
// Base = round-8/10 (best, 246-247us): f16 GEMM1 dbuf barrier-light + ping-pong,
// MX-fp8 GEMM2 (unit scales), e4m3-byte hq/wq, division-free quant epilogues.

#define M_TOT 16384
#define D_DIM 1024
#define H_DIM 4096

typedef _Float16 f16x8 __attribute__((ext_vector_type(8)));
typedef _Float16 f16x4 __attribute__((ext_vector_type(4)));
typedef float f32x4 __attribute__((ext_vector_type(4)));
typedef int i32x4 __attribute__((ext_vector_type(4)));
typedef int i32x8 __attribute__((ext_vector_type(8)));

// global -> LDS direct copy, 16B per lane. LDS dest = wave-uniform base + lane*16.
__device__ __forceinline__ void gl16(const void* g, void* l) {
    __builtin_amdgcn_global_load_lds(
        (const __attribute__((address_space(1))) unsigned int*)(uintptr_t)g,
        (__attribute__((address_space(3))) unsigned int*)(unsigned int)(uintptr_t)l,
        16, 0, 0);
}

// positive-input e4m3 quantize (post-relu), division-free, RNE. Returns the
// quantized VALUE as f16 (exactly representable).
__device__ __forceinline__ _Float16 q_e4m3_pos(float v) {
    uint32_t t = __float_as_uint(v);
    uint32_t tn = (t + 0x7ffffu + ((t >> 20) & 1u)) & 0xfff00000u;
    float qn = __uint_as_float(tn);
    float qs = rintf(v * 512.0f) * 0.001953125f;
    return (_Float16)(v < 0.015625f ? qs : qn);
}

// ---- pre-pass: fp32 -> f16 (RNE), vectorized x4 ----
__global__ __launch_bounds__(256) void cvt_f16_kernel(
    const float* __restrict__ in, _Float16* __restrict__ out, int n4)
{
    int i = blockIdx.x * 256 + threadIdx.x;
    if (i >= n4) return;
    float4 v = reinterpret_cast<const float4*>(in)[i];
    f16x4 hv = {(_Float16)v.x, (_Float16)v.y, (_Float16)v.z, (_Float16)v.w};
    reinterpret_cast<f16x4*>(out)[i] = hv;
}

// ---- pre-pass: fp32 -> e4m3 BYTES via HW cvt (RNE, OCP grid == ref grid) ----
__global__ __launch_bounds__(256) void quant_e4m3_byte_kernel(
    const float* __restrict__ in, uint32_t* __restrict__ outq, int n4)
{
    int i = blockIdx.x * 256 + threadIdx.x;
    if (i >= n4) return;
    float4 v = reinterpret_cast<const float4*>(in)[i];
    uint32_t r = __builtin_amdgcn_cvt_pk_fp8_f32(v.x, v.y, 0, false);
    r = __builtin_amdgcn_cvt_pk_fp8_f32(v.z, v.w, r, true);
    outq[i] = r;
}

// ---- GEMM1: h=relu(xh@w1h^T+b1), q_e4m3, store BYTES. 256x256 BK=64 f16. ----
// Double-buffered 128KB, barrier-light K-loop + pinned A-frag read-ahead.
__global__ __launch_bounds__(512) void gemm1_f16(
    const _Float16* __restrict__ A, const _Float16* __restrict__ B,
    const float* __restrict__ bias, uint8_t* __restrict__ Cq)
{
    constexpr int K = D_DIM;   // 1024
    constexpr int N = H_DIM;   // 4096 (bytes per out row)
    __shared__ __align__(16) _Float16 smem[65536];   // 128 KiB
    _Float16* sA = smem;            // 2 x 16384
    _Float16* sB = smem + 32768;    // 2 x 16384

    const int tid  = threadIdx.x;
    const int lane = tid & 63;
    const int w    = tid >> 6;
    const int wr   = w >> 2, wc = w & 3;
    const int fr   = lane & 15, kq = lane >> 4;

    constexpr int NBX = N / 256;               // 16
    constexpr int NWG = (M_TOT / 256) * NBX;   // 1024
    constexpr int CPX = NWG / 8;
    int bid = blockIdx.y * NBX + blockIdx.x;
    bid = (bid & 7) * CPX + (bid >> 3);
    const int n0 = (bid % NBX) * 256;
    const int m0 = (bid / NBX) * 256;

    const int srow = tid >> 3;
    const int sseg = (tid & 7) ^ (srow & 7);
    const _Float16* gA = A + (size_t)(m0 + srow) * K + sseg * 8;
    const _Float16* gB = B + (size_t)(n0 + srow) * K + sseg * 8;
    const int ldsw = w * 512;
    const size_t R1 = (size_t)64 * K, R2 = (size_t)128 * K, R3 = (size_t)192 * K;

    const int xorv = fr & 7;
    const int cA0 = (kq ^ xorv) * 8;
    const int cA1 = ((kq + 4) ^ xorv) * 8;
    const int aRow = wr * 128 + fr;
    const int bRow = wc * 64 + fr;

    f32x4 acc[8][4];
#pragma unroll
    for (int i = 0; i < 8; i++)
#pragma unroll
        for (int j = 0; j < 4; j++) acc[i][j] = (f32x4){0.f, 0.f, 0.f, 0.f};

    f16x8 bfr[4][2];
    constexpr int NK = K / 64;   // 16

    gl16(gB,      sB + ldsw);
    gl16(gB + R1, sB + 4096 + ldsw);
    gl16(gB + R2, sB + 8192 + ldsw);
    gl16(gB + R3, sB + 12288 + ldsw);
    gl16(gA,      sA + ldsw);
    gl16(gA + R1, sA + 4096 + ldsw);
    gl16(gA + R2, sA + 8192 + ldsw);
    gl16(gA + R3, sA + 12288 + ldsw);
    asm volatile("s_waitcnt vmcnt(0)" ::: "memory");
    __builtin_amdgcn_s_barrier();
    asm volatile("" ::: "memory");

    for (int t = 0; t < NK; ++t) {
        const int c = t & 1;
        const _Float16* sAc = sA + c * 16384;
        const _Float16* sBc = sB + c * 16384;
        _Float16* sAn = sA + (c ^ 1) * 16384;
        _Float16* sBn = sB + (c ^ 1) * 16384;
        const bool pref = (t + 1 < NK);

        if (pref) {
            const _Float16* gAn = gA + (size_t)(t + 1) * 64;
            const _Float16* gBn = gB + (size_t)(t + 1) * 64;
            gl16(gBn,      sBn + ldsw);
            gl16(gBn + R1, sBn + 4096 + ldsw);
            gl16(gBn + R2, sBn + 8192 + ldsw);
            gl16(gBn + R3, sBn + 12288 + ldsw);
            gl16(gAn,      sAn + ldsw);
            gl16(gAn + R1, sAn + 4096 + ldsw);
            gl16(gAn + R2, sAn + 8192 + ldsw);
            gl16(gAn + R3, sAn + 12288 + ldsw);
        }

        // A-frag ping-pong: afr[p&1] consumed, afr[(p+1)&1] prefetched.
        f16x8 afr[2][2][2];
        // tile prologue: B (8 reads) + A phase-0 (4 reads)
#pragma unroll
        for (int ii = 0; ii < 2; ii++) {
            const _Float16* ra = sAc + (aRow + ii * 16) * 64;
            afr[0][ii][0] = *(const f16x8*)(ra + cA0);
            afr[0][ii][1] = *(const f16x8*)(ra + cA1);
        }
#pragma unroll
        for (int j = 0; j < 4; j++) {
            const _Float16* rb = sBc + (bRow + j * 16) * 64;
            bfr[j][0] = *(const f16x8*)(rb + cA0);
            bfr[j][1] = *(const f16x8*)(rb + cA1);
        }
#pragma unroll
        for (int p = 0; p < 4; ++p) {
            const int cur = p & 1, nxt = cur ^ 1;
            if (p < 3) {
                // issue phase p+1's reads BEFORE phase p's MFMAs
#pragma unroll
                for (int ii = 0; ii < 2; ii++) {
                    const _Float16* ra = sAc + (aRow + (2 * (p + 1) + ii) * 16) * 64;
                    afr[nxt][ii][0] = *(const f16x8*)(ra + cA0);
                    afr[nxt][ii][1] = *(const f16x8*)(ra + cA1);
                }
            }
            // pin: reads stay ABOVE the MFMA cluster in the emitted schedule
            __builtin_amdgcn_sched_barrier(0);
#pragma unroll
            for (int ii = 0; ii < 2; ii++)
#pragma unroll
                for (int j = 0; j < 4; j++) {
                    acc[2*p+ii][j] = __builtin_amdgcn_mfma_f32_16x16x32_f16(
                        afr[cur][ii][0], bfr[j][0], acc[2*p+ii][j], 0, 0, 0);
                    acc[2*p+ii][j] = __builtin_amdgcn_mfma_f32_16x16x32_f16(
                        afr[cur][ii][1], bfr[j][1], acc[2*p+ii][j], 0, 0, 0);
                }
        }

        asm volatile("s_waitcnt vmcnt(0)" ::: "memory");
        __builtin_amdgcn_s_barrier();
        asm volatile("" ::: "memory");
    }

    // epilogue: +bias, relu, q_e4m3 (f16 value) -> swizzled LDS [256][256] f16
    // tile -> read f16x8, convert to 8 e4m3 bytes (exact), coalesced 8B stores.
    const int col0 = n0 + wc * 64 + fr;
    float bv[4];
#pragma unroll
    for (int j = 0; j < 4; j++) bv[j] = bias[col0 + j * 16];
    const int sub = (fr & 7) * 2;
    const int slotbase = wc * 8 + (fr >> 3);
    const int rowbase = wr * 128 + kq * 4;
#pragma unroll
    for (int i = 0; i < 8; i++) {
        const int trow0 = rowbase + i * 16;
#pragma unroll
        for (int r = 0; r < 4; r++) {
            const int trow = trow0 + r;
            const int swz = (((kq & 1) * 4 + r)) ^ (kq >> 1);  // == (trow&7)^((trow>>3)&1)
#pragma unroll
            for (int j = 0; j < 4; j++) {
                float v = fmaxf(acc[i][j][r] + bv[j], 0.0f);
                _Float16 q = q_e4m3_pos(v);
                int byte = trow * 512 + (((slotbase + j * 2) ^ swz) << 4) + sub;
                *(_Float16*)((char*)smem + byte) = q;
            }
        }
    }
    __syncthreads();
#pragma unroll
    for (int cch = 0; cch < 16; cch++) {
        int flat = cch * 512 + tid;
        int row  = flat >> 5;
        int slot = flat & 31;
        int swz  = (row & 7) ^ ((row >> 3) & 1);
        f16x8 v8 = *(const f16x8*)((char*)smem + row * 512 + ((slot ^ swz) << 4));
        uint32_t u0 = __builtin_amdgcn_cvt_pk_fp8_f32((float)v8[0], (float)v8[1], 0, false);
        u0 = __builtin_amdgcn_cvt_pk_fp8_f32((float)v8[2], (float)v8[3], u0, true);
        uint32_t u1 = __builtin_amdgcn_cvt_pk_fp8_f32((float)v8[4], (float)v8[5], 0, false);
        u1 = __builtin_amdgcn_cvt_pk_fp8_f32((float)v8[6], (float)v8[7], u1, true);
        uint2 u = {u0, u1};
        *(uint2*)(Cq + (size_t)(m0 + row) * N + n0 + slot * 8) = u;
    }
}

// ---- GEMM2: out = hq @ wq^T + b2q (MX-fp8, unit scales), q_e5m10, fp32 out ----
// A[16384,4096] bytes, B[1024,4096] bytes, NT. 256x256 tile, BK=128 bytes.
// Dbuf form + pinned A-frag read-ahead (no setprio).
__global__ __launch_bounds__(512) void gemm2_fp8(
    const uint8_t* __restrict__ A, const uint8_t* __restrict__ B,
    const float* __restrict__ b2, float* __restrict__ C)
{
    constexpr int Kb = H_DIM;  // 4096 bytes per row
    constexpr int N  = D_DIM;  // 1024
    __shared__ __align__(16) uint8_t smem[131072];
    uint8_t* sA = smem;            // 2 x 32768
    uint8_t* sB = smem + 65536;    // 2 x 32768

    const int tid  = threadIdx.x;
    const int lane = tid & 63;
    const int w    = tid >> 6;
    const int wr   = w >> 2, wc = w & 3;
    const int fr   = lane & 15, kq = lane >> 4;

    constexpr int NBX = N / 256;               // 4
    constexpr int NWG = (M_TOT / 256) * NBX;   // 256
    constexpr int CPX = NWG / 8;
    int bid = blockIdx.y * NBX + blockIdx.x;
    bid = (bid & 7) * CPX + (bid >> 3);
    const int n0 = (bid % NBX) * 256;
    const int m0 = (bid / NBX) * 256;

    const int srow = tid >> 3;
    const int sseg = (tid & 7) ^ (srow & 7);     // 16B-slot pre-swizzle
    const uint8_t* gA = A + (size_t)(m0 + srow) * Kb + sseg * 16;
    const uint8_t* gB = B + (size_t)(n0 + srow) * Kb + sseg * 16;
    const int ldsw = w * 1024;                   // bytes per wave per round
    const size_t R1 = (size_t)64 * Kb, R2 = (size_t)128 * Kb, R3 = (size_t)192 * Kb;

    const int xorv = fr & 7;
    const int sO0 = ((2 * kq) ^ xorv) * 16;
    const int sO1 = ((2 * kq + 1) ^ xorv) * 16;
    const int aRowB = (wr * 128 + fr) * 128;
    const int bRowB = (wc * 64 + fr) * 128;

    f32x4 acc[8][4];
#pragma unroll
    for (int i = 0; i < 8; i++)
#pragma unroll
        for (int j = 0; j < 4; j++) acc[i][j] = (f32x4){0.f, 0.f, 0.f, 0.f};

    i32x8 bfr[4];
    constexpr int NK = Kb / 128;   // 32
    constexpr uint32_t SC1 = 0x7f7f7f7fu;   // e8m0 unit scale in every byte

    gl16(gB,      sB + ldsw);
    gl16(gB + R1, sB + 8192 + ldsw);
    gl16(gB + R2, sB + 16384 + ldsw);
    gl16(gB + R3, sB + 24576 + ldsw);
    gl16(gA,      sA + ldsw);
    gl16(gA + R1, sA + 8192 + ldsw);
    gl16(gA + R2, sA + 16384 + ldsw);
    gl16(gA + R3, sA + 24576 + ldsw);
    asm volatile("s_waitcnt vmcnt(0)" ::: "memory");
    __builtin_amdgcn_s_barrier();
    asm volatile("" ::: "memory");

    for (int t = 0; t < NK; ++t) {
        const int c = t & 1;
        const uint8_t* sAc = sA + c * 32768;
        const uint8_t* sBc = sB + c * 32768;
        uint8_t* sAn = sA + (c ^ 1) * 32768;
        uint8_t* sBn = sB + (c ^ 1) * 32768;
        const bool pref = (t + 1 < NK);

        if (pref) {
            const uint8_t* gAn = gA + (size_t)(t + 1) * 128;
            const uint8_t* gBn = gB + (size_t)(t + 1) * 128;
            gl16(gBn,      sBn + ldsw);
            gl16(gBn + R1, sBn + 8192 + ldsw);
            gl16(gBn + R2, sBn + 16384 + ldsw);
            gl16(gBn + R3, sBn + 24576 + ldsw);
            gl16(gAn,      sAn + ldsw);
            gl16(gAn + R1, sAn + 8192 + ldsw);
            gl16(gAn + R2, sAn + 16384 + ldsw);
            gl16(gAn + R3, sAn + 24576 + ldsw);
        }

        // A-frag ping-pong: af[p&1] consumed, af[(p+1)&1] prefetched.
        i32x8 af[2][2];
#pragma unroll
        for (int ii = 0; ii < 2; ii++) {
            const uint8_t* ra = sAc + aRowB + ii * 2048;
            i32x4 lo = *(const i32x4*)(ra + sO0);
            i32x4 hi = *(const i32x4*)(ra + sO1);
            af[0][ii] = (i32x8){lo.x, lo.y, lo.z, lo.w, hi.x, hi.y, hi.z, hi.w};
        }
#pragma unroll
        for (int j = 0; j < 4; j++) {
            const uint8_t* rb = sBc + bRowB + j * 2048;
            i32x4 lo = *(const i32x4*)(rb + sO0);
            i32x4 hi = *(const i32x4*)(rb + sO1);
            bfr[j] = (i32x8){lo.x, lo.y, lo.z, lo.w, hi.x, hi.y, hi.z, hi.w};
        }
#pragma unroll
        for (int p = 0; p < 4; ++p) {
            const int cur = p & 1, nxt = cur ^ 1;
            if (p < 3) {
#pragma unroll
                for (int ii = 0; ii < 2; ii++) {
                    const uint8_t* ra = sAc + aRowB + (2 * (p + 1) + ii) * 2048;
                    i32x4 lo = *(const i32x4*)(ra + sO0);
                    i32x4 hi = *(const i32x4*)(ra + sO1);
                    af[nxt][ii] = (i32x8){lo.x, lo.y, lo.z, lo.w, hi.x, hi.y, hi.z, hi.w};
                }
            }
            // pin: reads stay ABOVE the MFMA cluster in the emitted schedule
            __builtin_amdgcn_sched_barrier(0);
#pragma unroll
            for (int ii = 0; ii < 2; ii++)
#pragma unroll
                for (int j = 0; j < 4; j++) {
                    acc[2*p+ii][j] = __builtin_amdgcn_mfma_scale_f32_16x16x128_f8f6f4(
                        af[cur][ii], bfr[j], acc[2*p+ii][j],
                        0, 0,            // cbsz=FP8, blgp=FP8
                        0, SC1,          // opsel_a, scale_a (1.0)
                        0, SC1);         // opsel_b, scale_b (1.0)
                }
        }

        asm volatile("s_waitcnt vmcnt(0)" ::: "memory");
        __builtin_amdgcn_s_barrier();
        asm volatile("" ::: "memory");
    }

    // epilogue: + q_e5m10(b2), quantize e5m10 (f16 RNE roundtrip), store fp32
    const int col0 = n0 + wc * 64 + fr;
    const int row0 = m0 + wr * 128 + kq * 4;
#pragma unroll
    for (int j = 0; j < 4; j++) {
        const float bq = (float)(_Float16)b2[col0 + j * 16];
#pragma unroll
        for (int i = 0; i < 8; i++) {
            size_t base = (size_t)(row0 + i * 16) * N + (col0 + j * 16);
#pragma unroll
            for (int r = 0; r < 4; r++) {
                float v = acc[i][j][r] + bq;
                C[base + (size_t)r * N] = (float)(_Float16)v;
            }
        }
    }
}

extern "C" void kernel_launch(void* const* d_in, const int* in_sizes, int n_in,
                              void* d_out, int out_size, void* d_ws, size_t ws_size,
                              hipStream_t stream) {
    const float* x  = (const float*)d_in[0];   // [16384,1024]
    const float* w1 = (const float*)d_in[1];   // [4096,1024]
    const float* b1 = (const float*)d_in[2];   // [4096]
    const float* w2 = (const float*)d_in[3];   // [1024,4096]
    const float* b2 = (const float*)d_in[4];   // [1024]
    float* out = (float*)d_out;

    // workspace layout (bytes):
    // hq  e4m3 bytes [16384,4096] :  67,108,864
    // xh  f16 [16384,1024]        :  33,554,432
    // w1h f16 [4096,1024]         :   8,388,608
    // wq  e4m3 bytes [1024,4096]  :   4,194,304
    const size_t need = 67108864ull + 33554432ull + 8388608ull + 4194304ull;
    if (ws_size < need) return;  // fail visibly (output stays zero)

    char* ws = (char*)d_ws;
    uint8_t*  hq  = (uint8_t*)ws;
    _Float16* xh  = (_Float16*)(ws + 67108864ull);
    _Float16* w1h = xh + 16777216;
    uint8_t*  wq  = (uint8_t*)(w1h + 4194304);

    cvt_f16_kernel<<<16384, 256, 0, stream>>>(x, xh, 4194304);
    cvt_f16_kernel<<<4096, 256, 0, stream>>>(w1, w1h, 1048576);
    quant_e4m3_byte_kernel<<<4096, 256, 0, stream>>>(w2, (uint32_t*)wq, 1048576);

    // GEMM1: M=16384, N=4096, K=1024 -> grid (16,64) = 1024 wg
    gemm1_f16<<<dim3(H_DIM / 256, M_TOT / 256), 512, 0, stream>>>(xh, w1h, b1, hq);
    // GEMM2: M=16384, N=1024, K=4096 bytes -> grid (4,64) = 256 wg
    gemm2_fp8<<<dim3(D_DIM / 256, M_TOT / 256), 512, 0, stream>>>(hq, wq, b2, out);
}

// Round 10
// 228.844 us; speedup vs baseline: 3.6603x; 1.0217x over previous
//
#include <hip/hip_runtime.h>
#include <stdint.h>

// FFN: x[16384,1024] -> relu(x@W1^T+b1)[16384,4096] -> q_e4m3 -> @W2^T+b2 -> q_e5m10
// Round 12: 2 blocks/CU via small-acc tiles. Six schedule variants pinned the
// 256²/8-wave kernels at serial(MFMA + LDS) — all waves at the same pipeline
// position, 1 block/CU (240 regs/wave, 128KB LDS). The proven overlap mechanism
// is co-resident independent blocks (m114); round-7 failed only because acc=128
// regs can't fit the 128-reg/wave budget 4 waves/SIMD needs. Fix: tile 128x256,
// 8 waves of 64x64 -> acc=64, total ~115 regs, __launch_bounds__(512,4);
// single-buffer LDS (G1 64KB incl. epilogue buffer, G2 48KB) -> 2 blocks/CU.
// Per tile: compute -> bar -> stage -> vmcnt(0) -> bar; the exposed stage-wait
// is hidden by the partner block's compute (blocks desync across generations).
// Per-element accumulation sequence unchanged -> bit-identical output.
// Keeps round-9 wins: no setprio, sched_barrier(0) pin, ping-pong (G1).

#define M_TOT 16384
#define D_DIM 1024
#define H_DIM 4096

typedef _Float16 f16x8 __attribute__((ext_vector_type(8)));
typedef _Float16 f16x4 __attribute__((ext_vector_type(4)));
typedef float f32x4 __attribute__((ext_vector_type(4)));
typedef int i32x4 __attribute__((ext_vector_type(4)));
typedef int i32x8 __attribute__((ext_vector_type(8)));

// global -> LDS direct copy, 16B per lane. LDS dest = wave-uniform base + lane*16.
__device__ __forceinline__ void gl16(const void* g, void* l) {
    __builtin_amdgcn_global_load_lds(
        (const __attribute__((address_space(1))) unsigned int*)(uintptr_t)g,
        (__attribute__((address_space(3))) unsigned int*)(unsigned int)(uintptr_t)l,
        16, 0, 0);
}

// positive-input e4m3 quantize (post-relu), division-free, RNE. Returns the
// quantized VALUE as f16 (exactly representable).
__device__ __forceinline__ _Float16 q_e4m3_pos(float v) {
    uint32_t t = __float_as_uint(v);
    uint32_t tn = (t + 0x7ffffu + ((t >> 20) & 1u)) & 0xfff00000u;
    float qn = __uint_as_float(tn);
    float qs = rintf(v * 512.0f) * 0.001953125f;
    return (_Float16)(v < 0.015625f ? qs : qn);
}

// ---- pre-pass: fp32 -> f16 (RNE), vectorized x4 ----
__global__ __launch_bounds__(256) void cvt_f16_kernel(
    const float* __restrict__ in, _Float16* __restrict__ out, int n4)
{
    int i = blockIdx.x * 256 + threadIdx.x;
    if (i >= n4) return;
    float4 v = reinterpret_cast<const float4*>(in)[i];
    f16x4 hv = {(_Float16)v.x, (_Float16)v.y, (_Float16)v.z, (_Float16)v.w};
    reinterpret_cast<f16x4*>(out)[i] = hv;
}

// ---- pre-pass: fp32 -> e4m3 BYTES via HW cvt (RNE, OCP grid == ref grid) ----
__global__ __launch_bounds__(256) void quant_e4m3_byte_kernel(
    const float* __restrict__ in, uint32_t* __restrict__ outq, int n4)
{
    int i = blockIdx.x * 256 + threadIdx.x;
    if (i >= n4) return;
    float4 v = reinterpret_cast<const float4*>(in)[i];
    uint32_t r = __builtin_amdgcn_cvt_pk_fp8_f32(v.x, v.y, 0, false);
    r = __builtin_amdgcn_cvt_pk_fp8_f32(v.z, v.w, r, true);
    outq[i] = r;
}

// ---- GEMM1: h=relu(xh@w1h^T+b1), q_e4m3, store BYTES. 128x256 BK=64 f16. ----
// 8 waves (2M x 4N) of 64x64; acc=64 regs; single-buffer 48KB staging inside a
// 64KB LDS block (epilogue transpose uses all 64KB). 2 blocks/CU.
__global__ __launch_bounds__(512, 4) void gemm1_f16(
    const _Float16* __restrict__ A, const _Float16* __restrict__ B,
    const float* __restrict__ bias, uint8_t* __restrict__ Cq)
{
    constexpr int K = D_DIM;   // 1024
    constexpr int N = H_DIM;   // 4096 (bytes per out row)
    __shared__ __align__(16) _Float16 smem[32768];   // 64 KiB
    _Float16* sA = smem;            // [128][64] = 8192 f16 (16KB)
    _Float16* sB = smem + 8192;     // [256][64] = 16384 f16 (32KB)

    const int tid  = threadIdx.x;
    const int lane = tid & 63;
    const int w    = tid >> 6;
    const int wr   = w >> 2, wc = w & 3;   // per-wave C: 64 rows x 64 cols
    const int fr   = lane & 15, kq = lane >> 4;

    constexpr int NBX = N / 256;               // 16
    constexpr int NWG = (M_TOT / 128) * NBX;   // 2048
    constexpr int CPX = NWG / 8;
    int bid = blockIdx.y * NBX + blockIdx.x;
    bid = (bid & 7) * CPX + (bid >> 3);
    const int n0 = (bid % NBX) * 256;
    const int m0 = (bid / NBX) * 128;

    // staging: round = 64 rows x 128B = 8KB; A: 2 rounds, B: 4 rounds.
    const int srow = tid >> 3;
    const int sseg = (tid & 7) ^ (srow & 7);
    const _Float16* gA = A + (size_t)(m0 + srow) * K + sseg * 8;
    const _Float16* gB = B + (size_t)(n0 + srow) * K + sseg * 8;
    const int ldsw = w * 512;                        // f16 per wave per round
    const size_t R1 = (size_t)64 * K, R2 = (size_t)128 * K, R3 = (size_t)192 * K;

    const int xorv = fr & 7;
    const int cA0 = (kq ^ xorv) * 8;
    const int cA1 = ((kq + 4) ^ xorv) * 8;
    const int aRow = wr * 64 + fr;
    const int bRow = wc * 64 + fr;

    f32x4 acc[4][4];
#pragma unroll
    for (int i = 0; i < 4; i++)
#pragma unroll
        for (int j = 0; j < 4; j++) acc[i][j] = (f32x4){0.f, 0.f, 0.f, 0.f};

    f16x8 bfr[4][2];
    constexpr int NK = K / 64;   // 16

    // prologue: stage tile 0 (B r0-3, A r0-1), drain, barrier.
    gl16(gB,      sB + ldsw);
    gl16(gB + R1, sB + 4096 + ldsw);
    gl16(gB + R2, sB + 8192 + ldsw);
    gl16(gB + R3, sB + 12288 + ldsw);
    gl16(gA,      sA + ldsw);
    gl16(gA + R1, sA + 4096 + ldsw);
    asm volatile("s_waitcnt vmcnt(0)" ::: "memory");
    __builtin_amdgcn_s_barrier();
    asm volatile("" ::: "memory");

    for (int t = 0; t < NK; ++t) {
        // ---- compute tile t from the single buffer ----
#pragma unroll
        for (int j = 0; j < 4; j++) {
            const _Float16* rb = sB + (bRow + j * 16) * 64;
            bfr[j][0] = *(const f16x8*)(rb + cA0);
            bfr[j][1] = *(const f16x8*)(rb + cA1);
        }
        f16x8 afr[2][2];
        {
            const _Float16* ra = sA + aRow * 64;
            afr[0][0] = *(const f16x8*)(ra + cA0);
            afr[0][1] = *(const f16x8*)(ra + cA1);
        }
#pragma unroll
        for (int i = 0; i < 4; ++i) {
            const int cur = i & 1, nxt = cur ^ 1;
            if (i < 3) {
                const _Float16* ra = sA + (aRow + (i + 1) * 16) * 64;
                afr[nxt][0] = *(const f16x8*)(ra + cA0);
                afr[nxt][1] = *(const f16x8*)(ra + cA1);
            }
            __builtin_amdgcn_sched_barrier(0);
#pragma unroll
            for (int j = 0; j < 4; j++) {
                acc[i][j] = __builtin_amdgcn_mfma_f32_16x16x32_f16(
                    afr[cur][0], bfr[j][0], acc[i][j], 0, 0, 0);
                acc[i][j] = __builtin_amdgcn_mfma_f32_16x16x32_f16(
                    afr[cur][1], bfr[j][1], acc[i][j], 0, 0, 0);
            }
        }
        // all waves done reading tile t
        asm volatile("" ::: "memory");
        __builtin_amdgcn_s_barrier();
        asm volatile("" ::: "memory");

        if (t + 1 < NK) {
            // stage tile t+1 into the same buffer; the drain is dead time for
            // THIS block, covered by the co-resident partner block's compute.
            const _Float16* gAn = gA + (size_t)(t + 1) * 64;
            const _Float16* gBn = gB + (size_t)(t + 1) * 64;
            gl16(gBn,      sB + ldsw);
            gl16(gBn + R1, sB + 4096 + ldsw);
            gl16(gBn + R2, sB + 8192 + ldsw);
            gl16(gBn + R3, sB + 12288 + ldsw);
            gl16(gAn,      sA + ldsw);
            gl16(gAn + R1, sA + 4096 + ldsw);
            asm volatile("s_waitcnt vmcnt(0)" ::: "memory");
            __builtin_amdgcn_s_barrier();
            asm volatile("" ::: "memory");
        }
    }

    // epilogue: +bias, relu, q_e4m3 (f16 value) -> swizzled LDS [128][256] f16
    // tile (64KB, one pass) -> read f16x8, cvt to e4m3 bytes, coalesced stores.
    const int col0 = n0 + wc * 64 + fr;
    float bv[4];
#pragma unroll
    for (int j = 0; j < 4; j++) bv[j] = bias[col0 + j * 16];
    const int sub = (fr & 7) * 2;
    const int slotbase = wc * 8 + (fr >> 3);
    const int rowbase = wr * 64 + kq * 4;
#pragma unroll
    for (int i = 0; i < 4; i++) {
        const int trow0 = rowbase + i * 16;
#pragma unroll
        for (int r = 0; r < 4; r++) {
            const int trow = trow0 + r;
            const int swz = ((kq & 1) * 4 + r) ^ (kq >> 1);  // == (trow&7)^((trow>>3)&1)
#pragma unroll
            for (int j = 0; j < 4; j++) {
                float v = fmaxf(acc[i][j][r] + bv[j], 0.0f);
                _Float16 q = q_e4m3_pos(v);
                int byte = trow * 512 + (((slotbase + j * 2) ^ swz) << 4) + sub;
                *(_Float16*)((char*)smem + byte) = q;
            }
        }
    }
    __syncthreads();
#pragma unroll
    for (int cch = 0; cch < 8; cch++) {
        int flat = cch * 512 + tid;          // 16B-chunk index, 4096 total
        int row  = flat >> 5;                // 0..127
        int slot = flat & 31;
        int swz  = (row & 7) ^ ((row >> 3) & 1);
        f16x8 v8 = *(const f16x8*)((char*)smem + row * 512 + ((slot ^ swz) << 4));
        uint32_t u0 = __builtin_amdgcn_cvt_pk_fp8_f32((float)v8[0], (float)v8[1], 0, false);
        u0 = __builtin_amdgcn_cvt_pk_fp8_f32((float)v8[2], (float)v8[3], u0, true);
        uint32_t u1 = __builtin_amdgcn_cvt_pk_fp8_f32((float)v8[4], (float)v8[5], 0, false);
        u1 = __builtin_amdgcn_cvt_pk_fp8_f32((float)v8[6], (float)v8[7], u1, true);
        uint2 u = {u0, u1};
        *(uint2*)(Cq + (size_t)(m0 + row) * N + n0 + slot * 8) = u;
    }
}

// ---- GEMM2: out = hq @ wq^T + b2q (MX-fp8, unit scales), q_e5m10, fp32 out ----
// 128x256 tile, BK=128 bytes, 8 waves of 64x64; acc=64; 48KB single-buffer LDS;
// 2 blocks/CU. Grid (4,128) = 512 wg.
__global__ __launch_bounds__(512, 4) void gemm2_fp8(
    const uint8_t* __restrict__ A, const uint8_t* __restrict__ B,
    const float* __restrict__ b2, float* __restrict__ C)
{
    constexpr int Kb = H_DIM;  // 4096 bytes per row
    constexpr int N  = D_DIM;  // 1024
    __shared__ __align__(16) uint8_t smem[49152];    // 48 KiB
    uint8_t* sA = smem;            // [128][128B] = 16KB
    uint8_t* sB = smem + 16384;    // [256][128B] = 32KB

    const int tid  = threadIdx.x;
    const int lane = tid & 63;
    const int w    = tid >> 6;
    const int wr   = w >> 2, wc = w & 3;   // per-wave C: 64 rows x 64 cols
    const int fr   = lane & 15, kq = lane >> 4;

    constexpr int NBX = N / 256;               // 4
    constexpr int NWG = (M_TOT / 128) * NBX;   // 512
    constexpr int CPX = NWG / 8;
    int bid = blockIdx.y * NBX + blockIdx.x;
    bid = (bid & 7) * CPX + (bid >> 3);
    const int n0 = (bid % NBX) * 256;
    const int m0 = (bid / NBX) * 128;

    const int srow = tid >> 3;
    const int sseg = (tid & 7) ^ (srow & 7);     // 16B-slot pre-swizzle
    const uint8_t* gA = A + (size_t)(m0 + srow) * Kb + sseg * 16;
    const uint8_t* gB = B + (size_t)(n0 + srow) * Kb + sseg * 16;
    const int ldsw = w * 1024;                   // bytes per wave per round
    const size_t R1 = (size_t)64 * Kb, R2 = (size_t)128 * Kb, R3 = (size_t)192 * Kb;

    const int xorv = fr & 7;
    const int sO0 = ((2 * kq) ^ xorv) * 16;
    const int sO1 = ((2 * kq + 1) ^ xorv) * 16;
    const int aRowB = (wr * 64 + fr) * 128;
    const int bRowB = (wc * 64 + fr) * 128;

    f32x4 acc[4][4];
#pragma unroll
    for (int i = 0; i < 4; i++)
#pragma unroll
        for (int j = 0; j < 4; j++) acc[i][j] = (f32x4){0.f, 0.f, 0.f, 0.f};

    i32x8 bfr[4];
    constexpr int NK = Kb / 128;   // 32
    constexpr uint32_t SC1 = 0x7f7f7f7fu;   // e8m0 unit scale in every byte

    gl16(gB,      sB + ldsw);
    gl16(gB + R1, sB + 8192 + ldsw);
    gl16(gB + R2, sB + 16384 + ldsw);
    gl16(gB + R3, sB + 24576 + ldsw);
    gl16(gA,      sA + ldsw);
    gl16(gA + R1, sA + 8192 + ldsw);
    asm volatile("s_waitcnt vmcnt(0)" ::: "memory");
    __builtin_amdgcn_s_barrier();
    asm volatile("" ::: "memory");

    for (int t = 0; t < NK; ++t) {
        // ---- compute tile t ----
#pragma unroll
        for (int j = 0; j < 4; j++) {
            const uint8_t* rb = sB + bRowB + j * 2048;
            i32x4 lo = *(const i32x4*)(rb + sO0);
            i32x4 hi = *(const i32x4*)(rb + sO1);
            bfr[j] = (i32x8){lo.x, lo.y, lo.z, lo.w, hi.x, hi.y, hi.z, hi.w};
        }
#pragma unroll
        for (int i = 0; i < 4; ++i) {
            const uint8_t* ra = sA + aRowB + i * 2048;
            i32x4 lo = *(const i32x4*)(ra + sO0);
            i32x4 hi = *(const i32x4*)(ra + sO1);
            i32x8 af = (i32x8){lo.x, lo.y, lo.z, lo.w, hi.x, hi.y, hi.z, hi.w};
            __builtin_amdgcn_sched_barrier(0);
#pragma unroll
            for (int j = 0; j < 4; j++) {
                acc[i][j] = __builtin_amdgcn_mfma_scale_f32_16x16x128_f8f6f4(
                    af, bfr[j], acc[i][j],
                    0, 0,            // cbsz=FP8, blgp=FP8
                    0, SC1,          // opsel_a, scale_a (1.0)
                    0, SC1);         // opsel_b, scale_b (1.0)
            }
        }
        asm volatile("" ::: "memory");
        __builtin_amdgcn_s_barrier();
        asm volatile("" ::: "memory");

        if (t + 1 < NK) {
            const uint8_t* gAn = gA + (size_t)(t + 1) * 128;
            const uint8_t* gBn = gB + (size_t)(t + 1) * 128;
            gl16(gBn,      sB + ldsw);
            gl16(gBn + R1, sB + 8192 + ldsw);
            gl16(gBn + R2, sB + 16384 + ldsw);
            gl16(gBn + R3, sB + 24576 + ldsw);
            gl16(gAn,      sA + ldsw);
            gl16(gAn + R1, sA + 8192 + ldsw);
            asm volatile("s_waitcnt vmcnt(0)" ::: "memory");
            __builtin_amdgcn_s_barrier();
            asm volatile("" ::: "memory");
        }
    }

    // epilogue: + q_e5m10(b2), quantize e5m10 (f16 RNE roundtrip), store fp32
    const int col0 = n0 + wc * 64 + fr;
    const int row0 = m0 + wr * 64 + kq * 4;
#pragma unroll
    for (int j = 0; j < 4; j++) {
        const float bq = (float)(_Float16)b2[col0 + j * 16];
#pragma unroll
        for (int i = 0; i < 4; i++) {
            size_t base = (size_t)(row0 + i * 16) * N + (col0 + j * 16);
#pragma unroll
            for (int r = 0; r < 4; r++) {
                float v = acc[i][j][r] + bq;
                C[base + (size_t)r * N] = (float)(_Float16)v;
            }
        }
    }
}

extern "C" void kernel_launch(void* const* d_in, const int* in_sizes, int n_in,
                              void* d_out, int out_size, void* d_ws, size_t ws_size,
                              hipStream_t stream) {
    const float* x  = (const float*)d_in[0];   // [16384,1024]
    const float* w1 = (const float*)d_in[1];   // [4096,1024]
    const float* b1 = (const float*)d_in[2];   // [4096]
    const float* w2 = (const float*)d_in[3];   // [1024,4096]
    const float* b2 = (const float*)d_in[4];   // [1024]
    float* out = (float*)d_out;

    // workspace layout (bytes):
    // hq  e4m3 bytes [16384,4096] :  67,108,864
    // xh  f16 [16384,1024]        :  33,554,432
    // w1h f16 [4096,1024]         :   8,388,608
    // wq  e4m3 bytes [1024,4096]  :   4,194,304
    const size_t need = 67108864ull + 33554432ull + 8388608ull + 4194304ull;
    if (ws_size < need) return;  // fail visibly (output stays zero)

    char* ws = (char*)d_ws;
    uint8_t*  hq  = (uint8_t*)ws;
    _Float16* xh  = (_Float16*)(ws + 67108864ull);
    _Float16* w1h = xh + 16777216;
    uint8_t*  wq  = (uint8_t*)(w1h + 4194304);

    cvt_f16_kernel<<<16384, 256, 0, stream>>>(x, xh, 4194304);
    cvt_f16_kernel<<<4096, 256, 0, stream>>>(w1, w1h, 1048576);
    quant_e4m3_byte_kernel<<<4096, 256, 0, stream>>>(w2, (uint32_t*)wq, 1048576);

    // GEMM1: M=16384, N=4096, K=1024 -> grid (16,128) = 2048 wg, 2 blocks/CU
    gemm1_f16<<<dim3(H_DIM / 256, M_TOT / 128), 512, 0, stream>>>(xh, w1h, b1, hq);
    // GEMM2: M=16384, N=1024, K=4096 bytes -> grid (4,128) = 512 wg, 2 blocks/CU
    gemm2_fp8<<<dim3(D_DIM / 256, M_TOT / 128), 512, 0, stream>>>(hq, wq, b2, out);
}